// Round 10
// baseline (459.904 us; speedup 1.0000x reference)
//
#include <hip/hip_runtime.h>
#include <hip/hip_bf16.h>
#include <hip/hip_cooperative_groups.h>

typedef __attribute__((ext_vector_type(8))) short short8;
typedef __attribute__((ext_vector_type(4))) float f32x4;

constexpr int Bb = 8, NN = 2048, FIN = 512, FOUT = 256;
#define LRALPHA 0.2f
#define MFMA16(a, b, c) __builtin_amdgcn_mfma_f32_16x16x32_bf16((a), (b), (c), 0, 0, 0)

static __device__ __forceinline__ ushort f2bf(float f) {
    unsigned u = __float_as_uint(f);
    u += 0x7fffu + ((u >> 16) & 1u);
    return (ushort)(u >> 16);
}
static __device__ __forceinline__ float bf2f(ushort b) { return __uint_as_float(((unsigned)b) << 16); }

// LDS-only barrier: waits ds ops but leaves global loads (vmcnt) in flight.
#define LDSBAR() do { asm volatile("s_waitcnt lgkmcnt(0)" ::: "memory"); \
                      __builtin_amdgcn_s_barrier(); \
                      asm volatile("" ::: "memory"); } while (0)
#define BARONLY() do { asm volatile("" ::: "memory"); \
                       __builtin_amdgcn_s_barrier(); \
                       asm volatile("" ::: "memory"); } while (0)

struct SPrep { float r1[2][4]; float r2[2][4]; };
struct SGemm { ushort Ah[4][2][512]; ushort Tr[8][16][72]; };
struct SGat  { float t_l[NN]; ushort Pf[2][4][2][512]; float den_l[64]; };

// ---------------------------------------------------------------------------
// Phase 0: block bid (0..255):
//  - wa: rows k = 2*bid, 2*bid+1 : wa[k] = W[k,:]·a
//  - WT: row n = bid: CONTIGUOUS 4B writes (fixes cross-XCD 2B scatter),
//        reads W column n (read-only, L2-shared).
// ---------------------------------------------------------------------------
static __device__ void prep_body(int bid, int t, SPrep& s,
                                 const float* __restrict__ W, const float* __restrict__ a,
                                 ushort* __restrict__ WTh, ushort* __restrict__ WTl,
                                 float* __restrict__ wa1, float* __restrict__ wa2) {
    const int half = t >> 8, n = t & 255, lane = t & 63, w4 = (t >> 6) & 3;
    const int k = bid * 2 + half;
    const float wv = W[(size_t)k * FOUT + n];
    float p1 = wv * a[n], p2 = wv * a[FOUT + n];
#pragma unroll
    for (int m = 1; m < 64; m <<= 1) {
        p1 += __shfl_xor(p1, m);
        p2 += __shfl_xor(p2, m);
    }
    if (lane == 0) { s.r1[half][w4] = p1; s.r2[half][w4] = p2; }
    if (t < 256) {
        const float w0 = W[(size_t)(2 * t) * FOUT + bid];
        const float w1 = W[(size_t)(2 * t + 1) * FOUT + bid];
        const ushort h0 = f2bf(w0), h1 = f2bf(w1);
        const ushort l0 = f2bf(w0 - bf2f(h0)), l1 = f2bf(w1 - bf2f(h1));
        *(unsigned int*)(WTh + (size_t)bid * FIN + 2 * t) = (unsigned int)h0 | ((unsigned int)h1 << 16);
        *(unsigned int*)(WTl + (size_t)bid * FIN + 2 * t) = (unsigned int)l0 | ((unsigned int)l1 << 16);
    }
    __syncthreads();
    if (n == 0) {
        wa1[k] = s.r1[half][0] + s.r1[half][1] + s.r1[half][2] + s.r1[half][3];
        wa2[k] = s.r2[half][0] + s.r2[half][1] + s.r2[half][2] + s.r2[half][3];
    }
}

// ---------------------------------------------------------------------------
// Phase 1: h = x @ W (xh*(Wh+Wl)) + exact fp32 s/t dots + transposed bf16 hT.
// 64m x 256n tile, m0 = bid*64. (R8 body, verified.)
// ---------------------------------------------------------------------------
static __device__ void gemm_body(int bid, int t, SGemm& s,
                                 const float* __restrict__ x,
                                 const ushort* __restrict__ WTh, const ushort* __restrict__ WTl,
                                 const float* __restrict__ wa1, const float* __restrict__ wa2,
                                 ushort* __restrict__ hTh,
                                 float* __restrict__ sv, float* __restrict__ tv) {
    const int lane = t & 63, w = t >> 6;
    const int m0 = bid * 64;

    const int lr = t >> 3, c8 = (t & 7) * 8;
    const int aif = lr >> 4, akstep = c8 >> 5, ak8 = (c8 >> 3) & 3;
    ushort* adst = &s.Ah[aif][akstep][(((ak8 << 4) | (lr & 15))) * 8];
    const float* xp = x + (size_t)(m0 + lr) * FIN + c8;

    const size_t b0 = (size_t)(w * 32 + (lane & 15)) * FIN + (lane >> 4) * 8;
    const size_t b1 = b0 + (size_t)16 * FIN;
    const ushort *ph0 = WTh + b0, *pl0 = WTl + b0;
    const ushort *ph1 = WTh + b1, *pl1 = WTl + b1;

    f32x4 acc[4][2];
#pragma unroll
    for (int f = 0; f < 4; ++f) {
        acc[f][0] = (f32x4){0.f, 0.f, 0.f, 0.f};
        acc[f][1] = (f32x4){0.f, 0.f, 0.f, 0.f};
    }
    float sp = 0.f, tp = 0.f;

    float4 xa0 = *(const float4*)(xp + 0),  xa1 = *(const float4*)(xp + 4);
    float4 xb0 = *(const float4*)(xp + 64), xb1 = *(const float4*)(xp + 68);
    float4 xc0, xc1, xd0, xd1;
    short8 A00 = *(const short8*)(ph0 + 0),  A01 = *(const short8*)(pl0 + 0);
    short8 A02 = *(const short8*)(ph0 + 32), A03 = *(const short8*)(pl0 + 32);
    short8 A10 = *(const short8*)(ph1 + 0),  A11 = *(const short8*)(pl1 + 0);
    short8 A12 = *(const short8*)(ph1 + 32), A13 = *(const short8*)(pl1 + 32);
    short8 B00, B01, B02, B03, B10, B11, B12, B13;

    auto phase = [&](int kt, const float4& c0, const float4& c1, float4& nx0, float4& nx1,
                     const short8& g00, const short8& g01, const short8& g02, const short8& g03,
                     const short8& g10, const short8& g11, const short8& g12, const short8& g13,
                     short8& n00, short8& n01, short8& n02, short8& n03,
                     short8& n10, short8& n11, short8& n12, short8& n13) {
        const int k0 = kt * 64;
        const float fv[8] = {c0.x, c0.y, c0.z, c0.w, c1.x, c1.y, c1.z, c1.w};
        short8 vh;
#pragma unroll
        for (int e = 0; e < 8; ++e) vh[e] = (short)f2bf(fv[e]);
        const float4 w1a = *(const float4*)(wa1 + k0 + c8);
        const float4 w1b = *(const float4*)(wa1 + k0 + c8 + 4);
        const float4 w2a = *(const float4*)(wa2 + k0 + c8);
        const float4 w2b = *(const float4*)(wa2 + k0 + c8 + 4);
        sp += fv[0]*w1a.x + fv[1]*w1a.y + fv[2]*w1a.z + fv[3]*w1a.w
            + fv[4]*w1b.x + fv[5]*w1b.y + fv[6]*w1b.z + fv[7]*w1b.w;
        tp += fv[0]*w2a.x + fv[1]*w2a.y + fv[2]*w2a.z + fv[3]*w2a.w
            + fv[4]*w2b.x + fv[5]*w2b.y + fv[6]*w2b.z + fv[7]*w2b.w;
        BARONLY();
        *(short8*)adst = vh;
        LDSBAR();
        const int kx = (kt + 2 < 8 ? kt + 2 : 7) * 64;
        nx0 = *(const float4*)(xp + kx);
        nx1 = *(const float4*)(xp + kx + 4);
        const int kb = (kt + 1 < 8 ? kt + 1 : 7) * 64;
        n00 = *(const short8*)(ph0 + kb);      n01 = *(const short8*)(pl0 + kb);
        n02 = *(const short8*)(ph0 + kb + 32); n03 = *(const short8*)(pl0 + kb + 32);
        n10 = *(const short8*)(ph1 + kb);      n11 = *(const short8*)(pl1 + kb);
        n12 = *(const short8*)(ph1 + kb + 32); n13 = *(const short8*)(pl1 + kb + 32);
#pragma unroll
        for (int f = 0; f < 4; ++f) {
            const short8 a0 = *(const short8*)&s.Ah[f][0][lane * 8];
            const short8 a1 = *(const short8*)&s.Ah[f][1][lane * 8];
            acc[f][0] = MFMA16(a0, g00, acc[f][0]);
            acc[f][0] = MFMA16(a0, g01, acc[f][0]);
            acc[f][0] = MFMA16(a1, g02, acc[f][0]);
            acc[f][0] = MFMA16(a1, g03, acc[f][0]);
            acc[f][1] = MFMA16(a0, g10, acc[f][1]);
            acc[f][1] = MFMA16(a0, g11, acc[f][1]);
            acc[f][1] = MFMA16(a1, g12, acc[f][1]);
            acc[f][1] = MFMA16(a1, g13, acc[f][1]);
        }
    };

    for (int kt = 0; kt < 8; kt += 4) {
        phase(kt + 0, xa0, xa1, xc0, xc1, A00,A01,A02,A03,A10,A11,A12,A13,
                                           B00,B01,B02,B03,B10,B11,B12,B13);
        phase(kt + 1, xb0, xb1, xd0, xd1, B00,B01,B02,B03,B10,B11,B12,B13,
                                           A00,A01,A02,A03,A10,A11,A12,A13);
        phase(kt + 2, xc0, xc1, xa0, xa1, A00,A01,A02,A03,A10,A11,A12,A13,
                                           B00,B01,B02,B03,B10,B11,B12,B13);
        phase(kt + 3, xd0, xd1, xb0, xb1, B00,B01,B02,B03,B10,B11,B12,B13,
                                           A00,A01,A02,A03,A10,A11,A12,A13);
    }

    sp += __shfl_xor(sp, 1, 8); sp += __shfl_xor(sp, 2, 8); sp += __shfl_xor(sp, 4, 8);
    tp += __shfl_xor(tp, 1, 8); tp += __shfl_xor(tp, 2, 8); tp += __shfl_xor(tp, 4, 8);
    if ((t & 7) == 0) {
        sv[m0 + lr] = sp;
        tv[m0 + lr] = tp;
    }

    const int rb = (lane >> 4) * 4;
    const int c = lane >> 2, rowb = (lane & 3) * 16;
#pragma unroll
    for (int p = 0; p < 2; ++p) {
        __syncthreads();
#pragma unroll
        for (int f = 0; f < 4; ++f)
#pragma unroll
            for (int r = 0; r < 4; ++r)
                s.Tr[w][lane & 15][f * 16 + rb + r] = f2bf(acc[f][p][r]);
        __syncthreads();
        const ushort* src = &s.Tr[w][c][rowb];
        const short8 v0 = *(const short8*)src;
        const short8 v1 = *(const short8*)(src + 8);
        ushort* dst = hTh + ((size_t)(m0 >> 11) * FOUT + w * 32 + p * 16 + c) * NN
                      + (m0 & 2047) + rowb;
        *(short8*)dst = v0;
        *(short8*)(dst + 8) = v1;
    }
}

// ---------------------------------------------------------------------------
// Phase 2: fused masked softmax + P@H (MFMA) + elu. (R8 body, verified.)
// b = bid&7 (XCD affinity), i0 = (bid>>3)*64.
// ---------------------------------------------------------------------------
static __device__ void gat_body(int bid, int t, SGat& s,
                                const int* __restrict__ adj,
                                const ushort* __restrict__ hTh,
                                const float* __restrict__ sv, const float* __restrict__ tv,
                                float* __restrict__ out) {
    const int lane = t & 63, w = t >> 6;
    const int b = bid & 7, i0 = (bid >> 3) * 64;

    *(float4*)&s.t_l[t * 4] = *(const float4*)&tv[b * NN + t * 4];

    const int r = t >> 3, jn = (t & 7) * 8;
    const float s_i = sv[b * NN + i0 + r];
    const int* adjp = adj + ((size_t)b * NN + i0 + r) * NN + jn;
    const int pif = r >> 4, pkstep = jn >> 5, pk8 = (jn >> 3) & 3;
    ushort* pdst0 = &s.Pf[0][pif][pkstep][((pk8 << 4) | (r & 15)) * 8];
    ushort* pdst1 = &s.Pf[1][pif][pkstep][((pk8 << 4) | (r & 15)) * 8];

    const ushort* hb = hTh + (size_t)b * FOUT * NN;
    const ushort* h00 = hb + (size_t)(2 * w * 16 + (lane & 15)) * NN + (lane >> 4) * 8;
    const ushort* h10 = hb + (size_t)((2 * w + 1) * 16 + (lane & 15)) * NN + (lane >> 4) * 8;

    f32x4 acc[4][2];
#pragma unroll
    for (int f = 0; f < 4; ++f) {
        acc[f][0] = (f32x4){0.f, 0.f, 0.f, 0.f};
        acc[f][1] = (f32x4){0.f, 0.f, 0.f, 0.f};
    }
    float den_part = 0.f;

    int4 ajA0 = *(const int4*)(adjp +   0), ajA1 = *(const int4*)(adjp +   4);
    int4 ajB0 = *(const int4*)(adjp +  64), ajB1 = *(const int4*)(adjp +  68);
    int4 ajC0 = *(const int4*)(adjp + 128), ajC1 = *(const int4*)(adjp + 132);
    int4 ajD0 = *(const int4*)(adjp + 192), ajD1 = *(const int4*)(adjp + 196);
    short8 X00 = *(const short8*)h00,        X01 = *(const short8*)(h00 + 32);
    short8 X10 = *(const short8*)h10,        X11 = *(const short8*)(h10 + 32);
    short8 Y00 = *(const short8*)(h00 + 64), Y01 = *(const short8*)(h00 + 96);
    short8 Y10 = *(const short8*)(h10 + 64), Y11 = *(const short8*)(h10 + 96);

    __syncthreads();   // t_l ready

    auto phase = [&](int jt, ushort* pdst, int rbuf,
                     int4& as0, int4& as1,
                     short8& H00, short8& H01, short8& H10, short8& H11) {
        const int j0 = jt * 64;
        const int avs[8] = {as0.x, as0.y, as0.z, as0.w, as1.x, as1.y, as1.z, as1.w};
        const int jA = min(j0 + 256, NN - 64);
        as0 = *(const int4*)(adjp + jA);
        as1 = *(const int4*)(adjp + jA + 4);
        const float4 tq0 = *(const float4*)&s.t_l[j0 + jn];
        const float4 tq1 = *(const float4*)&s.t_l[j0 + jn + 4];
        const float tvv[8] = {tq0.x, tq0.y, tq0.z, tq0.w, tq1.x, tq1.y, tq1.z, tq1.w};
        short8 pv;
#pragma unroll
        for (int e = 0; e < 8; ++e) {
            float v = s_i + tvv[e];
            v = v > 0.f ? v : LRALPHA * v;
            const float wv = avs[e] > 0 ? __expf(v) : 0.f;
            const ushort hbv = f2bf(wv);
            den_part += bf2f(hbv);
            pv[e] = (short)hbv;
        }
        *(short8*)pdst = pv;
        LDSBAR();
        const ushort* pr = &s.Pf[rbuf][0][0][0] + lane * 8;
        __builtin_amdgcn_s_setprio(1);
#pragma unroll
        for (int f = 0; f < 4; ++f) {
            const short8 a0 = *(const short8*)(pr + f * 1024);
            const short8 a1 = *(const short8*)(pr + f * 1024 + 512);
            acc[f][0] = MFMA16(a0, H00, acc[f][0]);
            acc[f][0] = MFMA16(a1, H01, acc[f][0]);
            acc[f][1] = MFMA16(a0, H10, acc[f][1]);
            acc[f][1] = MFMA16(a1, H11, acc[f][1]);
        }
        __builtin_amdgcn_s_setprio(0);
        const int jH = min(j0 + 128, NN - 64);
        H00 = *(const short8*)(h00 + jH);
        H01 = *(const short8*)(h00 + jH + 32);
        H10 = *(const short8*)(h10 + jH);
        H11 = *(const short8*)(h10 + jH + 32);
    };

    for (int tt = 0; tt < NN / 64; tt += 4) {
        phase(tt + 0, pdst0, 0, ajA0, ajA1, X00, X01, X10, X11);
        phase(tt + 1, pdst1, 1, ajB0, ajB1, Y00, Y01, Y10, Y11);
        phase(tt + 2, pdst0, 0, ajC0, ajC1, X00, X01, X10, X11);
        phase(tt + 3, pdst1, 1, ajD0, ajD1, Y00, Y01, Y10, Y11);
    }

    den_part += __shfl_xor(den_part, 1, 8);
    den_part += __shfl_xor(den_part, 2, 8);
    den_part += __shfl_xor(den_part, 4, 8);
    if ((t & 7) == 0) s.den_l[r] = den_part;
    __syncthreads();

    const int rb = (lane >> 4) * 4;
#pragma unroll
    for (int f = 0; f < 4; ++f) {
#pragma unroll
        for (int rr = 0; rr < 4; ++rr) {
            const int row = f * 16 + rb + rr;
            const float inv = 1.0f / s.den_l[row];
#pragma unroll
            for (int cf = 0; cf < 2; ++cf) {
                float v = acc[f][cf][rr] * inv;
                v = v > 0.f ? v : expm1f(v);
                out[((size_t)b * NN + i0 + row) * FOUT + w * 32 + cf * 16 + (lane & 15)] = v;
            }
        }
    }
}

// ---------------------------------------------------------------------------
// Cooperative mono-kernel: prep -> grid.sync -> gemm -> grid.sync -> gat.
// One dispatch: visible in rocprof top-5 with full counters.
// ---------------------------------------------------------------------------
union SMU { SPrep p; SGemm g; SGat q; };

__global__ __launch_bounds__(512, 2) void gat_mono(const float* x, const int* adj,
                                                   const float* W, const float* a,
                                                   ushort* WTh, ushort* WTl,
                                                   float* wa1, float* wa2,
                                                   ushort* hTh, float* sv, float* tv,
                                                   float* out) {
    __shared__ SMU sm;
    const int bid = blockIdx.x, t = threadIdx.x;
    prep_body(bid, t, sm.p, W, a, WTh, WTl, wa1, wa2);
    __threadfence();
    cooperative_groups::this_grid().sync();
    gemm_body(bid, t, sm.g, x, WTh, WTl, wa1, wa2, hTh, sv, tv);
    __threadfence();
    cooperative_groups::this_grid().sync();
    gat_body(bid, t, sm.q, adj, hTh, sv, tv, out);
}

// Fallback path (regular launches) in case cooperative capture is unsupported.
__global__ __launch_bounds__(512, 2) void k_prep(const float* W, const float* a,
                                                 ushort* WTh, ushort* WTl,
                                                 float* wa1, float* wa2) {
    __shared__ SPrep s;
    prep_body(blockIdx.x, threadIdx.x, s, W, a, WTh, WTl, wa1, wa2);
}
__global__ __launch_bounds__(512, 2) void k_gemm(const float* x, const ushort* WTh,
                                                 const ushort* WTl, const float* wa1,
                                                 const float* wa2, ushort* hTh,
                                                 float* sv, float* tv) {
    __shared__ SGemm s;
    gemm_body(blockIdx.x, threadIdx.x, s, x, WTh, WTl, wa1, wa2, hTh, sv, tv);
}
__global__ __launch_bounds__(512, 2) void k_gat(const int* adj, const ushort* hTh,
                                                const float* sv, const float* tv,
                                                float* out) {
    __shared__ SGat s;
    gat_body(blockIdx.x, threadIdx.x, s, adj, hTh, sv, tv, out);
}

// ---------------------------------------------------------------------------
extern "C" void kernel_launch(void* const* d_in, const int* in_sizes, int n_in,
                              void* d_out, int out_size, void* d_ws, size_t ws_size,
                              hipStream_t stream) {
    const float* x   = (const float*)d_in[0];
    const int*   adj = (const int*)d_in[1];
    const float* W   = (const float*)d_in[2];
    const float* a   = (const float*)d_in[3];
    float* out = (float*)d_out;

    ushort* hTh = (ushort*)d_ws;
    float*  sv  = (float*)(hTh + (size_t)Bb * FOUT * NN);
    float*  tv  = sv + Bb * NN;
    ushort* WTh = (ushort*)(tv + Bb * NN);
    ushort* WTl = WTh + (size_t)FIN * FOUT;
    float*  wa1 = (float*)(WTl + (size_t)FIN * FOUT);
    float*  wa2 = wa1 + FIN;

    void* args[] = {(void*)&x, (void*)&adj, (void*)&W, (void*)&a,
                    (void*)&WTh, (void*)&WTl, (void*)&wa1, (void*)&wa2,
                    (void*)&hTh, (void*)&sv, (void*)&tv, (void*)&out};
    hipError_t e = hipLaunchCooperativeKernel(reinterpret_cast<const void*>(&gat_mono),
                                              dim3(256), dim3(512), args, 0u, stream);
    if (e != hipSuccess) {
        k_prep<<<256, 512, 0, stream>>>(W, a, WTh, WTl, wa1, wa2);
        k_gemm<<<256, 512, 0, stream>>>(x, WTh, WTl, wa1, wa2, hTh, sv, tv);
        k_gat<<<256, 512, 0, stream>>>(adj, hTh, sv, tv, out);
    }
}